// Round 2
// baseline (6342.253 us; speedup 1.0000x reference)
//
#include <hip/hip_runtime.h>
#include <hip/hip_cooperative_groups.h>
#include <stdint.h>

namespace cg = cooperative_groups;

// Borůvka maximum-spanning-forest == Kruskal acceptance set under the strict
// total order (score desc, edge-index asc). One cooperative kernel runs all
// rounds; edge-list compaction shrinks per-round work geometrically.
#define V_NODES 100000
#define MAX_ROUNDS 24     // 2^17 > 1e5; converges in ~7-8 rounds, breaks early
#define NBLK 1024         // __launch_bounds__(256,4) => >=4 blocks/CU co-resident
#define NTHR 256

__device__ __forceinline__ int find_root(const int* __restrict__ parent, int v) {
    int p = parent[v];
    int pp = parent[p];
    while (p != pp) { p = pp; pp = parent[p]; }
    return p;
}

// key = (~monotone_f32(score) << 32) | edge_id — min-key == best edge
// (largest score, ties -> smallest index, matching stable argsort(-scores)).
// Recomputed deterministically each use; no key array needed.
__device__ __forceinline__ unsigned long long edge_key(
        const float* __restrict__ s, const float* __restrict__ u, int id) {
    float sp = 1.0f / (1.0f + expf(-s[id]));                // sigmoid, f32 chain
    float g  = -logf(-logf(u[id] + 1e-9f) + 1e-9f);         // gumbel, f32 chain
    unsigned int b = __float_as_uint(sp + g);
    unsigned int m = (b & 0x80000000u) ? ~b : (b | 0x80000000u);
    return ((unsigned long long)(~m) << 32) | (unsigned int)id;
}

__global__ void __launch_bounds__(NTHR, 4) boruvka_coop(
    const float* __restrict__ s, const float* __restrict__ u,
    const int* __restrict__ ei, float* __restrict__ out,
    unsigned long long* __restrict__ best, int* __restrict__ parent,
    int* __restrict__ hook, int* __restrict__ bufA, int* __restrict__ bufB,
    int* __restrict__ counts, int E)
{
    cg::grid_group grid = cg::this_grid();
    const int tid = blockIdx.x * NTHR + threadIdx.x;
    const int stride = NBLK * NTHR;
    const int lane = threadIdx.x & 63;
    const int* src = ei;
    const int* dst = ei + E;

    // ---- init ----
    for (int v = tid; v < V_NODES; v += stride) { parent[v] = v; best[v] = ~0ULL; hook[v] = -1; }
    for (int e = tid; e < E; e += stride) out[e] = 0.0f;   // harness poisons d_out
    if (tid < MAX_ROUNDS) counts[tid] = 0;
    __threadfence();
    grid.sync();
    __threadfence();

    int n = E;   // round 0 scans the raw edge array (identity list)
    for (int r = 0; r < MAX_ROUNDS; ++r) {
        int* wcnt = counts + r;
        int* wlist = (r & 1) ? bufB : bufA;          // round r writes survivors here
        const int* rlist = (r & 1) ? bufA : bufB;    // ...and reads round r-1's list

        // ---- scan: bid for each component's best crossing edge; compact survivors ----
        for (int i = tid; ; i += stride) {
            bool active = (i < n);
            if (!__any(active)) break;               // wave-uniform exit (lanes contiguous)
            bool keep = false;
            int id = 0;
            if (active) {
                id = (r == 0) ? i : rlist[i];
                int ru = find_root(parent, src[id]);
                int rv = find_root(parent, dst[id]);
                if (ru != rv) {
                    keep = true;
                    unsigned long long k = edge_key(s, u, id);
                    if (k < best[ru]) atomicMin(&best[ru], k);   // check-before-atomic
                    if (k < best[rv]) atomicMin(&best[rv], k);
                }
            }
            unsigned long long mask = __ballot(keep);
            if (mask) {                               // wave-aggregated append
                int leader = __ffsll(mask) - 1;
                int base = 0;
                if (lane == leader) base = atomicAdd(wcnt, __popcll(mask));
                base = __shfl(base, leader);
                if (keep) wlist[base + __popcll(mask & ((1ULL << lane) - 1ULL))] = id;
            }
        }
        __threadfence();
        grid.sync();
        __threadfence();

        int nn = __hip_atomic_load(wcnt, __ATOMIC_RELAXED, __HIP_MEMORY_SCOPE_AGENT);
        if (nn == 0) break;                           // uniform: all threads read same value

        // ---- choose: mark each root's best edge (cut property), propose hook ----
        for (int v = tid; v < V_NODES; v += stride) {
            unsigned long long k = best[v];
            if (k == ~0ULL) continue;
            int id = (int)(unsigned int)(k & 0xffffffffu);
            int ru = find_root(parent, src[id]);
            int rv = find_root(parent, dst[id]);
            int other = (ru == v) ? rv : ru;
            out[id] = 1.0f;
            // mutual pair (both roots chose same edge): only larger id hooks
            if (best[other] != k || v > other) hook[v] = other;
        }
        __threadfence();
        grid.sync();
        __threadfence();

        // ---- hook + reset + one pointer-jump (merged; races benign: parent
        // pointers only ever move toward an ancestor, find_root loops anyway) ----
        for (int v = tid; v < V_NODES; v += stride) {
            int h = hook[v];
            int pv;
            if (h >= 0) { parent[v] = h; hook[v] = -1; pv = h; }
            else pv = parent[v];
            best[v] = ~0ULL;
            int gp = parent[pv];
            if (pv != gp) parent[v] = gp;
        }
        __threadfence();
        grid.sync();
        __threadfence();

        n = nn;
    }
}

extern "C" void kernel_launch(void* const* d_in, const int* in_sizes, int n_in,
                              void* d_out, int out_size, void* d_ws, size_t ws_size,
                              hipStream_t stream) {
    const float* s  = (const float*)d_in[0];
    const float* u  = (const float*)d_in[1];
    const int*   ei = (const int*)d_in[2];
    int E = in_sizes[0];
    float* out = (float*)d_out;

    char* ws = (char*)d_ws;
    unsigned long long* best = (unsigned long long*)ws;        // V*8 = 0.8 MB
    int* parent = (int*)(ws + (size_t)V_NODES * 8);            // V*4
    int* hook   = parent + V_NODES;                            // V*4
    int* bufA   = hook + V_NODES;                              // E*4 = 1.6 MB
    int* bufB   = bufA + E;                                    // E*4 = 1.6 MB
    int* counts = bufB + E;                                    // MAX_ROUNDS*4
    // total ~4.8 MB (R1 used 4.3 MB successfully)

    void* args[] = { (void*)&s, (void*)&u, (void*)&ei, (void*)&out,
                     (void*)&best, (void*)&parent, (void*)&hook,
                     (void*)&bufA, (void*)&bufB, (void*)&counts, (void*)&E };
    hipLaunchCooperativeKernel((const void*)boruvka_coop, dim3(NBLK), dim3(NTHR),
                               args, 0, stream);
}

// Round 3
// 1137.508 us; speedup vs baseline: 5.5756x; 5.5756x over previous
//
#include <hip/hip_runtime.h>
#include <stdint.h>

// Borůvka maximum-spanning-forest == Kruskal acceptance set under the strict
// total order (score desc, edge-index asc). Multi-launch graph (kernel
// boundaries are the cheap barrier on gfx950 — coop grid.sync costs ~135MB of
// cache-flush refetch, measured R2). Per round: scan+compact, choose, hook+
// full-path-compress. Survivor lists carry the 64-bit key (no recompute).
#define V_NODES 100000
#define MAX_ROUNDS 17   // components halve per active round; 2^17 > 1e5

__device__ __forceinline__ int find_root(const int* __restrict__ parent, int v) {
    int p = parent[v];
    int pp = parent[p];
    while (p != pp) { p = pp; pp = parent[p]; }   // depth <=2-3 after compression
    return p;
}

// key = (~monotone_f32(score) << 32) | edge_id — min-key == best edge
// (largest score, ties -> smallest index, matching stable argsort(-scores)).
__device__ __forceinline__ unsigned long long make_key(float sv, float uv, int id) {
    float sp = 1.0f / (1.0f + expf(-sv));                 // sigmoid, f32 chain
    float g  = -logf(-logf(uv + 1e-9f) + 1e-9f);          // gumbel, f32 chain
    unsigned int b = __float_as_uint(sp + g);
    unsigned int m = (b & 0x80000000u) ? ~b : (b | 0x80000000u);
    return ((unsigned long long)(~m) << 32) | (unsigned int)id;
}

__global__ void k_init(int* __restrict__ parent, unsigned long long* __restrict__ best,
                       int* __restrict__ hook, int* __restrict__ counts) {
    int v = blockIdx.x * blockDim.x + threadIdx.x;
    if (v < MAX_ROUNDS) counts[v] = 0;
    if (v >= V_NODES) return;
    parent[v] = v;
    best[v] = ~0ULL;
    hook[v] = -1;
}

// Round 0: roots are the vertices themselves (no parent reads). Computes keys
// once, zeros out[], bids, and compacts the key list for round 1.
__global__ void k_scan0(const float* __restrict__ s, const float* __restrict__ u,
                        const int* __restrict__ src, const int* __restrict__ dst,
                        float* __restrict__ out,
                        unsigned long long* __restrict__ best,
                        unsigned long long* __restrict__ wlist,
                        int* __restrict__ wcnt, int E) {
    int e = blockIdx.x * blockDim.x + threadIdx.x;
    int lane = threadIdx.x & 63;
    bool keep = false;
    unsigned long long k = 0;
    if (e < E) {
        out[e] = 0.0f;                      // harness poisons d_out each call
        int a = src[e], b = dst[e];
        if (a != b) {                       // self-loops never accepted
            keep = true;
            k = make_key(s[e], u[e], e);
            if (k < __hip_atomic_load(&best[a], __ATOMIC_RELAXED, __HIP_MEMORY_SCOPE_AGENT))
                atomicMin(&best[a], k);
            if (k < __hip_atomic_load(&best[b], __ATOMIC_RELAXED, __HIP_MEMORY_SCOPE_AGENT))
                atomicMin(&best[b], k);
        }
    }
    unsigned long long mask = __ballot(keep);
    if (mask) {                             // wave-aggregated append
        int leader = __ffsll(mask) - 1;
        int base = 0;
        if (lane == leader) base = atomicAdd(wcnt, __popcll(mask));
        base = __shfl(base, leader);
        if (keep) wlist[base + __popcll(mask & ((1ULL << lane) - 1ULL))] = k;
    }
}

// Rounds >=1: read compacted key list, drop merged edges, bid, recompact.
__global__ void k_scan(const int* __restrict__ src, const int* __restrict__ dst,
                       const int* __restrict__ parent,
                       unsigned long long* __restrict__ best,
                       const unsigned long long* __restrict__ rlist,
                       unsigned long long* __restrict__ wlist,
                       const int* __restrict__ rcnt, int* __restrict__ wcnt) {
    int n = *rcnt;
    int i = blockIdx.x * blockDim.x + threadIdx.x;
    if (n == 0) return;
    int lane = threadIdx.x & 63;
    bool keep = false;
    unsigned long long k = 0;
    if (i < n) {
        k = rlist[i];
        int id = (int)(unsigned int)(k & 0xffffffffu);
        int ru = find_root(parent, src[id]);
        int rv = find_root(parent, dst[id]);
        if (ru != rv) {
            keep = true;
            if (k < __hip_atomic_load(&best[ru], __ATOMIC_RELAXED, __HIP_MEMORY_SCOPE_AGENT))
                atomicMin(&best[ru], k);    // check-before-atomic: late rounds
            if (k < __hip_atomic_load(&best[rv], __ATOMIC_RELAXED, __HIP_MEMORY_SCOPE_AGENT))
                atomicMin(&best[rv], k);    // become broadcast reads, no atomics
        }
    }
    unsigned long long mask = __ballot(keep);
    if (mask) {
        int leader = __ffsll(mask) - 1;
        int base = 0;
        if (lane == leader) base = atomicAdd(wcnt, __popcll(mask));
        base = __shfl(base, leader);
        if (keep) wlist[base + __popcll(mask & ((1ULL << lane) - 1ULL))] = k;
    }
}

// Per-root: mark the winning edge (cut property => in MSF), propose hook.
// Mutual pair (both roots chose the same edge) broken by root id.
__global__ void k_choose(const int* __restrict__ src, const int* __restrict__ dst,
                         const int* __restrict__ parent,
                         const unsigned long long* __restrict__ best,
                         int* __restrict__ hook, float* __restrict__ out,
                         const int* __restrict__ cnt) {
    if (*cnt == 0) return;
    int v = blockIdx.x * blockDim.x + threadIdx.x;
    if (v >= V_NODES) return;
    unsigned long long k = best[v];
    if (k == ~0ULL) return;
    int id = (int)(unsigned int)(k & 0xffffffffu);
    int ru = find_root(parent, src[id]);
    int rv = find_root(parent, dst[id]);
    int other = (ru == v) ? rv : ru;
    out[id] = 1.0f;
    if (best[other] != k || v > other) hook[v] = other;
}

// Apply hooks, reset best/hook, fully compress paths. Concurrent parent writes
// are benign: every write moves a pointer toward its final root (hook edges
// form a forest over old roots — mutual pairs were tie-broken in k_choose).
__global__ void k_hookc(int* __restrict__ parent, unsigned long long* __restrict__ best,
                        int* __restrict__ hook, const int* __restrict__ cnt) {
    if (*cnt == 0) return;
    int v = blockIdx.x * blockDim.x + threadIdx.x;
    if (v >= V_NODES) return;
    int h = hook[v];
    if (h >= 0) { parent[v] = h; hook[v] = -1; }
    best[v] = ~0ULL;
    int p = (h >= 0) ? h : parent[v];
    int pp = parent[p];
    while (p != pp) { p = pp; pp = parent[p]; }
    parent[v] = p;
}

extern "C" void kernel_launch(void* const* d_in, const int* in_sizes, int n_in,
                              void* d_out, int out_size, void* d_ws, size_t ws_size,
                              hipStream_t stream) {
    const float* s  = (const float*)d_in[0];
    const float* u  = (const float*)d_in[1];
    const int*   ei = (const int*)d_in[2];
    const int E = in_sizes[0];
    const int* src = ei;
    const int* dst = ei + E;
    float* out = (float*)d_out;

    char* ws = (char*)d_ws;                                   // 8B-aligned
    unsigned long long* bufA = (unsigned long long*)ws;       // E*8 = 3.2 MB
    unsigned long long* bufB = bufA + E;                      // E*8 = 3.2 MB
    unsigned long long* best = bufB + E;                      // V*8 = 0.8 MB
    int* parent  = (int*)(best + V_NODES);                    // V*4
    int* hook    = parent + V_NODES;                          // V*4
    int* counts  = hook + V_NODES;                            // MAX_ROUNDS*4
    // total ~8.0 MB

    const int tb = 256;
    const int gE = (E + tb - 1) / tb;
    const int gV = (V_NODES + tb - 1) / tb;

    k_init<<<gV, tb, 0, stream>>>(parent, best, hook, counts);
    k_scan0<<<gE, tb, 0, stream>>>(s, u, src, dst, out, best, bufA, counts, E);
    k_choose<<<gV, tb, 0, stream>>>(src, dst, parent, best, hook, out, counts);
    k_hookc<<<gV, tb, 0, stream>>>(parent, best, hook, counts);

    for (int r = 1; r < MAX_ROUNDS; ++r) {
        const unsigned long long* rl = (r & 1) ? bufA : bufB;
        unsigned long long*       wl = (r & 1) ? bufB : bufA;
        k_scan<<<gE, tb, 0, stream>>>(src, dst, parent, best, rl, wl,
                                      counts + r - 1, counts + r);
        k_choose<<<gV, tb, 0, stream>>>(src, dst, parent, best, hook, out, counts + r);
        k_hookc<<<gV, tb, 0, stream>>>(parent, best, hook, counts + r);
    }
}